// Round 9
// baseline (388.951 us; speedup 1.0000x reference)
//
#include <hip/hip_runtime.h>

#define BB 64
#define LL 512
#define TT 52
#define START_TAG 50
#define END_TAG 51

// ws layout: Prows (64*512*52 f32 = 6.8MB) then Bp (64*512*52 u8 = 1.7MB)
#define PROWS_ELEMS (BB * LL * TT)

__device__ __forceinline__ float rdlane(float v, int l) {
    return __int_as_float(__builtin_amdgcn_readlane(__float_as_int(v), l));
}

__device__ __forceinline__ int wave_masksum(const int* mrow, int lane) {
    int partial = 0;
    #pragma unroll
    for (int k = 0; k < LL / 64; ++k) partial += mrow[lane + 64 * k];
    #pragma unroll
    for (int off = 32; off >= 1; off >>= 1) partial += __shfl_xor(partial, off, 64);
    return partial;
}

// ---------------- K1: forward recurrence, VALUES ONLY ----------------
// One wave per batch. Lane j holds P[j]. No LDS, no barriers, no index
// extraction: per i just readlane + 2 adds + fmax (4 accumulator chains for
// short latency). P_t rows stored to ws (fire-and-forget) for K2/K3.
// Exact: value = max over i of (f + c[i]) + P[i]; max is order-independent.
__launch_bounds__(64, 1)
__global__ void k_forward(const float* __restrict__ feats,
                          const int* __restrict__ mask,
                          const float* __restrict__ trans,
                          float* __restrict__ Prows) {
    const int b = blockIdx.x;
    const int lane = threadIdx.x;

    const int n = wave_masksum(mask + b * LL, lane);   // [256,512], uniform

    float c[TT];
    #pragma unroll
    for (int i = 0; i < TT; ++i)
        c[i] = (lane < TT) ? trans[i * TT + lane] : 0.0f;

    const float* frow = feats + (size_t)b * LL * TT;
    float* arow = Prows + (size_t)b * LL * TT;

    float bestP = (lane < TT) ? (frow[lane] + c[START_TAG]) : -3.0e38f;
    if (lane < TT) arow[lane] = bestP;                 // P0

    // 4-deep feats prefetch ring
    float fr[4];
    #pragma unroll
    for (int d = 0; d < 4; ++d) {
        int tt = 1 + d; if (tt > LL - 1) tt = LL - 1;
        fr[d] = (lane < TT) ? frow[tt * TT + lane] : 0.0f;
    }

    auto step = [&](int t, float f) {
        // 4 independent max chains (13 deep each) -> short dependent latency
        float b0 = -3.0e38f, b1 = -3.0e38f, b2 = -3.0e38f, b3 = -3.0e38f;
        #pragma unroll
        for (int g = 0; g < 13; ++g) {
            b0 = fmaxf(b0, (f + c[4 * g + 0]) + rdlane(bestP, 4 * g + 0));
            b1 = fmaxf(b1, (f + c[4 * g + 1]) + rdlane(bestP, 4 * g + 1));
            b2 = fmaxf(b2, (f + c[4 * g + 2]) + rdlane(bestP, 4 * g + 2));
            b3 = fmaxf(b3, (f + c[4 * g + 3]) + rdlane(bestP, 4 * g + 3));
        }
        bestP = fmaxf(fmaxf(b0, b1), fmaxf(b2, b3));
        if (lane < TT) arow[t * TT + lane] = bestP;    // fire-and-forget
    };

    int t = 1;
    for (; t + 3 < n; t += 4) {
        #pragma unroll
        for (int d = 0; d < 4; ++d) {
            float f = fr[d];
            int tt = t + d + 4; if (tt > LL - 1) tt = LL - 1;
            fr[d] = (lane < TT) ? frow[tt * TT + lane] : 0.0f;
            step(t + d, f);
        }
    }
    for (int d = 0; t < n; ++t, ++d) step(t, fr[d]);
}

// ---------------- K2: parallel backpointer recompute ----------------
// grid (64 batches x 8 t-chunks) x 256 thr. Row t: lane i of the loaded P row
// holds P_{t-1}[i]; lane j computes argmax_i (f + c[i]) + P[i] with strict >
// ascending scan == first-max-wins == jnp.argmax, operands bit-identical to
// the reference. Massively parallel (4096 rows total), latency fully hidden.
__launch_bounds__(256, 1)
__global__ void k_bp(const float* __restrict__ feats,
                     const int* __restrict__ mask,
                     const float* __restrict__ trans,
                     const float* __restrict__ Prows,
                     unsigned char* __restrict__ Bp) {
    const int b = blockIdx.x;
    const int cch = blockIdx.y;        // 0..7
    const int tid = threadIdx.x;
    const int lane = tid & 63;
    const int w = tid >> 6;

    const int n = wave_masksum(mask + b * LL, lane);

    float c[TT];
    #pragma unroll
    for (int i = 0; i < TT; ++i)
        c[i] = (lane < TT) ? trans[i * TT + lane] : 0.0f;

    const float* frow = feats + (size_t)b * LL * TT;
    const float* arow = Prows + (size_t)b * LL * TT;
    unsigned char* brow = Bp + (size_t)b * LL * TT;

    const int t0 = cch * 64 + w * 16;
    for (int r = 0; r < 16; ++r) {
        int t = t0 + r;
        if (t < 1 || t >= n) continue;         // uniform per wave
        float preg = (lane < TT) ? arow[(t - 1) * TT + lane] : 0.0f;
        float f    = (lane < TT) ? frow[t * TT + lane] : 0.0f;
        float best = -3.0e38f;
        int bi = 0;
        #pragma unroll
        for (int i = 0; i < TT; ++i) {
            float v = (f + c[i]) + rdlane(preg, i);  // exact reference fp order
            bool gt = v > best;                      // strict >, ascending i
            best = gt ? v : best;
            bi   = gt ? i : bi;
        }
        if (lane < TT) brow[t * TT + lane] = (unsigned char)bi;
    }
}

// ---------------- K3: 32-chunk two-phase backtrace + output ----------------
__launch_bounds__(256, 1)
__global__ void k_back(const int* __restrict__ mask,
                       const float* __restrict__ trans,
                       const float* __restrict__ Prows,
                       const unsigned char* __restrict__ Bp,
                       int* __restrict__ out) {
    const int b = blockIdx.x;
    const int tid = threadIdx.x;
    const int lane = tid & 63;

    __shared__ int s_tags[LL];
    __shared__ unsigned char s_map[32 * TT];
    __shared__ int s_ent[32];

    const int n = wave_masksum(mask + b * LL, lane);

    // pointer0 = argmax_i ( P_{n-1}[i] + trans[i, END] ), min-index tie
    const float* arow = Prows + (size_t)b * LL * TT;
    float lv = -3.0e38f;
    int li = lane;
    if (lane < TT) lv = arow[(n - 1) * TT + lane] + trans[lane * TT + END_TAG];
    #pragma unroll
    for (int off = 32; off >= 1; off >>= 1) {
        float ov = __shfl_xor(lv, off, 64);
        int   oi = __shfl_xor(li, off, 64);
        if (ov > lv || (ov == lv && oi < li)) { lv = ov; li = oi; }
    }
    const int ptr0 = li;   // uniform

    #pragma unroll
    for (int k = 0; k < LL / 256; ++k) s_tags[tid + 256 * k] = 0;
    __syncthreads();

    const unsigned char* bb = Bp + (size_t)b * LL * TT;
    const int W  = n - 1;                 // walk length
    const int Sc = (W + 31) >> 5;         // per-chunk steps (>=8)

    // phase 1: 32*52 = 1664 walkers, 7 interleaved chains per thread
    {
        int xs[7], rowb[7], steps[7], kk[7], yy[7];
        #pragma unroll
        for (int c7 = 0; c7 < 7; ++c7) {
            int v = c7 * 256 + tid;
            bool act = v < 32 * TT;
            int k = act ? v / TT : 0;
            int y = act ? v - k * TT : 0;
            int g0 = k * Sc;
            int st = W - g0; if (st > Sc) st = Sc; if (st < 0) st = 0;
            steps[c7] = act ? st : 0;
            rowb[c7] = (n - 1 - g0) * TT;
            xs[c7] = y; kk[c7] = k; yy[c7] = y;
        }
        for (int s = 0; s < Sc; ++s) {
            #pragma unroll
            for (int c7 = 0; c7 < 7; ++c7) {
                if (s < steps[c7]) {
                    xs[c7] = bb[rowb[c7] + xs[c7]];
                    rowb[c7] -= TT;
                }
            }
        }
        #pragma unroll
        for (int c7 = 0; c7 < 7; ++c7) {
            if (c7 * 256 + tid < 32 * TT)
                s_map[kk[c7] * TT + yy[c7]] = (unsigned char)xs[c7];
        }
    }
    __syncthreads();
    if (tid == 0) {
        int e = ptr0; s_ent[0] = e;
        #pragma unroll
        for (int k = 1; k < 32; ++k) { e = s_map[(k - 1) * TT + e]; s_ent[k] = e; }
        s_tags[n - 1] = ptr0;
        s_tags[LL - 1] = ptr0;    // reference quirk: decode[L-1] = pointer0 always
    }
    __syncthreads();
    if (tid < 32) {
        int k = tid;
        int x = s_ent[k];
        int g0 = k * Sc;
        int st = W - g0; if (st > Sc) st = Sc; if (st < 0) st = 0;
        int rowb = (n - 1 - g0) * TT;
        for (int s = 0; s < st; ++s) {
            x = bb[rowb + x];
            rowb -= TT;
            s_tags[n - 2 - g0 - s] = x;
        }
    }
    __syncthreads();

    int* orow = out + b * LL;
    #pragma unroll
    for (int k = 0; k < LL / 256; ++k) orow[tid + 256 * k] = s_tags[tid + 256 * k];
}

extern "C" void kernel_launch(void* const* d_in, const int* in_sizes, int n_in,
                              void* d_out, int out_size, void* d_ws, size_t ws_size,
                              hipStream_t stream) {
    const float* feats = (const float*)d_in[0];
    const int*   mask  = (const int*)d_in[1];
    const float* trans = (const float*)d_in[2];
    int* out = (int*)d_out;

    float* Prows = (float*)d_ws;
    unsigned char* Bp = (unsigned char*)d_ws + (size_t)PROWS_ELEMS * sizeof(float);

    k_forward<<<dim3(BB), dim3(64), 0, stream>>>(feats, mask, trans, Prows);
    k_bp<<<dim3(BB, 8), dim3(256), 0, stream>>>(feats, mask, trans, Prows, Bp);
    k_back<<<dim3(BB), dim3(256), 0, stream>>>(mask, trans, Prows, Bp, out);
}

// Round 10
// 387.247 us; speedup vs baseline: 1.0044x; 1.0044x over previous
//
#include <hip/hip_runtime.h>

#define BB 64
#define LL 512
#define TT 52
#define START_TAG 50
#define END_TAG 51

// ws layout: Prows (64*512*52 f32 = 6.8MB) then Bp (64*512*52 u8 = 1.7MB)
#define PROWS_ELEMS (BB * LL * TT)

__device__ __forceinline__ float rdlane(float v, int l) {
    return __int_as_float(__builtin_amdgcn_readlane(__float_as_int(v), l));
}

__device__ __forceinline__ int wave_masksum(const int* mrow, int lane) {
    int partial = 0;
    #pragma unroll
    for (int k = 0; k < LL / 64; ++k) partial += mrow[lane + 64 * k];
    #pragma unroll
    for (int off = 32; off >= 1; off >>= 1) partial += __shfl_xor(partial, off, 64);
    return partial;
}

// ---------------- K1: forward recurrence, VALUES ONLY ----------------
// One wave per batch. Lane j holds P[j]. No LDS, no barriers, no index
// extraction. Step body INLINE (no lambda -- R9's lambda broke SROA: VGPR=36,
// c[] re-loaded from memory every step). Each c[i] is pinned into a VGPR via
// an opaque asm pass-through so the compiler cannot rematerialize the load.
// Exact: value = max over i of (f + c[i]) + P[i]; max is order-independent.
__launch_bounds__(64, 1)
__global__ void k_forward(const float* __restrict__ feats,
                          const int* __restrict__ mask,
                          const float* __restrict__ trans,
                          float* __restrict__ Prows) {
    const int b = blockIdx.x;
    const int lane = threadIdx.x;

    const int n = wave_masksum(mask + b * LL, lane);   // [256,512], uniform

    float c[TT];
    #pragma unroll
    for (int i = 0; i < TT; ++i)
        c[i] = (lane < TT) ? trans[i * TT + lane] : 0.0f;
    // pin each value into a VGPR: opaque def kills rematerialization
    #pragma unroll
    for (int i = 0; i < TT; ++i)
        __asm__("" : "+v"(c[i]));

    const float* frow = feats + (size_t)b * LL * TT;
    float* arow = Prows + (size_t)b * LL * TT;

    float bestP = (lane < TT) ? (frow[lane] + c[START_TAG]) : -3.0e38f;
    if (lane < TT) arow[lane] = bestP;                 // P0

    // 4-deep feats prefetch ring
    float fr[4];
    #pragma unroll
    for (int d = 0; d < 4; ++d) {
        int tt = 1 + d; if (tt > LL - 1) tt = LL - 1;
        fr[d] = (lane < TT) ? frow[tt * TT + lane] : 0.0f;
    }

    int t = 1;
    for (; t + 3 < n; t += 4) {
        #pragma unroll
        for (int d = 0; d < 4; ++d) {
            float f = fr[d];
            int tt = t + d + 4; if (tt > LL - 1) tt = LL - 1;
            fr[d] = (lane < TT) ? frow[tt * TT + lane] : 0.0f;

            float b0 = -3.0e38f, b1 = -3.0e38f, b2 = -3.0e38f, b3 = -3.0e38f;
            #pragma unroll
            for (int g = 0; g < 13; ++g) {
                b0 = fmaxf(b0, (f + c[4 * g + 0]) + rdlane(bestP, 4 * g + 0));
                b1 = fmaxf(b1, (f + c[4 * g + 1]) + rdlane(bestP, 4 * g + 1));
                b2 = fmaxf(b2, (f + c[4 * g + 2]) + rdlane(bestP, 4 * g + 2));
                b3 = fmaxf(b3, (f + c[4 * g + 3]) + rdlane(bestP, 4 * g + 3));
            }
            bestP = fmaxf(fmaxf(b0, b1), fmaxf(b2, b3));
            if (lane < TT) arow[(t + d) * TT + lane] = bestP;   // fire-and-forget
        }
    }
    for (int d = 0; t < n; ++t, ++d) {
        float f = fr[d];
        float b0 = -3.0e38f, b1 = -3.0e38f, b2 = -3.0e38f, b3 = -3.0e38f;
        #pragma unroll
        for (int g = 0; g < 13; ++g) {
            b0 = fmaxf(b0, (f + c[4 * g + 0]) + rdlane(bestP, 4 * g + 0));
            b1 = fmaxf(b1, (f + c[4 * g + 1]) + rdlane(bestP, 4 * g + 1));
            b2 = fmaxf(b2, (f + c[4 * g + 2]) + rdlane(bestP, 4 * g + 2));
            b3 = fmaxf(b3, (f + c[4 * g + 3]) + rdlane(bestP, 4 * g + 3));
        }
        bestP = fmaxf(fmaxf(b0, b1), fmaxf(b2, b3));
        if (lane < TT) arow[t * TT + lane] = bestP;
    }
}

// ---------------- K2: parallel backpointer recompute ----------------
// grid (64 batches x 8 t-chunks) x 256 thr. Lane j computes argmax_i
// (f + c[i]) + P_{t-1}[i] with strict > ascending scan == first-max-wins ==
// jnp.argmax, operands bit-identical to the reference.
__launch_bounds__(256, 1)
__global__ void k_bp(const float* __restrict__ feats,
                     const int* __restrict__ mask,
                     const float* __restrict__ trans,
                     const float* __restrict__ Prows,
                     unsigned char* __restrict__ Bp) {
    const int b = blockIdx.x;
    const int cch = blockIdx.y;        // 0..7
    const int tid = threadIdx.x;
    const int lane = tid & 63;
    const int w = tid >> 6;

    const int n = wave_masksum(mask + b * LL, lane);

    float c[TT];
    #pragma unroll
    for (int i = 0; i < TT; ++i)
        c[i] = (lane < TT) ? trans[i * TT + lane] : 0.0f;
    #pragma unroll
    for (int i = 0; i < TT; ++i)
        __asm__("" : "+v"(c[i]));

    const float* frow = feats + (size_t)b * LL * TT;
    const float* arow = Prows + (size_t)b * LL * TT;
    unsigned char* brow = Bp + (size_t)b * LL * TT;

    const int t0 = cch * 64 + w * 16;
    for (int r = 0; r < 16; ++r) {
        int t = t0 + r;
        if (t < 1 || t >= n) continue;         // uniform per wave
        float preg = (lane < TT) ? arow[(t - 1) * TT + lane] : 0.0f;
        float f    = (lane < TT) ? frow[t * TT + lane] : 0.0f;
        float best = -3.0e38f;
        int bi = 0;
        #pragma unroll
        for (int i = 0; i < TT; ++i) {
            float v = (f + c[i]) + rdlane(preg, i);  // exact reference fp order
            bool gt = v > best;                      // strict >, ascending i
            best = gt ? v : best;
            bi   = gt ? i : bi;
        }
        if (lane < TT) brow[t * TT + lane] = (unsigned char)bi;
    }
}

// ---------------- K3: 32-chunk two-phase backtrace + output ----------------
__launch_bounds__(256, 1)
__global__ void k_back(const int* __restrict__ mask,
                       const float* __restrict__ trans,
                       const float* __restrict__ Prows,
                       const unsigned char* __restrict__ Bp,
                       int* __restrict__ out) {
    const int b = blockIdx.x;
    const int tid = threadIdx.x;
    const int lane = tid & 63;

    __shared__ int s_tags[LL];
    __shared__ unsigned char s_map[32 * TT];
    __shared__ int s_ent[32];

    const int n = wave_masksum(mask + b * LL, lane);

    // pointer0 = argmax_i ( P_{n-1}[i] + trans[i, END] ), min-index tie
    const float* arow = Prows + (size_t)b * LL * TT;
    float lv = -3.0e38f;
    int li = lane;
    if (lane < TT) lv = arow[(n - 1) * TT + lane] + trans[lane * TT + END_TAG];
    #pragma unroll
    for (int off = 32; off >= 1; off >>= 1) {
        float ov = __shfl_xor(lv, off, 64);
        int   oi = __shfl_xor(li, off, 64);
        if (ov > lv || (ov == lv && oi < li)) { lv = ov; li = oi; }
    }
    const int ptr0 = li;   // uniform

    #pragma unroll
    for (int k = 0; k < LL / 256; ++k) s_tags[tid + 256 * k] = 0;
    __syncthreads();

    const unsigned char* bb = Bp + (size_t)b * LL * TT;
    const int W  = n - 1;                 // walk length
    const int Sc = (W + 31) >> 5;         // per-chunk steps (>=8)

    // phase 1: 32*52 = 1664 walkers, 7 interleaved chains per thread
    {
        int xs[7], rowb[7], steps[7], kk[7], yy[7];
        #pragma unroll
        for (int c7 = 0; c7 < 7; ++c7) {
            int v = c7 * 256 + tid;
            bool act = v < 32 * TT;
            int k = act ? v / TT : 0;
            int y = act ? v - k * TT : 0;
            int g0 = k * Sc;
            int st = W - g0; if (st > Sc) st = Sc; if (st < 0) st = 0;
            steps[c7] = act ? st : 0;
            rowb[c7] = (n - 1 - g0) * TT;
            xs[c7] = y; kk[c7] = k; yy[c7] = y;
        }
        for (int s = 0; s < Sc; ++s) {
            #pragma unroll
            for (int c7 = 0; c7 < 7; ++c7) {
                if (s < steps[c7]) {
                    xs[c7] = bb[rowb[c7] + xs[c7]];
                    rowb[c7] -= TT;
                }
            }
        }
        #pragma unroll
        for (int c7 = 0; c7 < 7; ++c7) {
            if (c7 * 256 + tid < 32 * TT)
                s_map[kk[c7] * TT + yy[c7]] = (unsigned char)xs[c7];
        }
    }
    __syncthreads();
    if (tid == 0) {
        int e = ptr0; s_ent[0] = e;
        #pragma unroll
        for (int k = 1; k < 32; ++k) { e = s_map[(k - 1) * TT + e]; s_ent[k] = e; }
        s_tags[n - 1] = ptr0;
        s_tags[LL - 1] = ptr0;    // reference quirk: decode[L-1] = pointer0 always
    }
    __syncthreads();
    if (tid < 32) {
        int k = tid;
        int x = s_ent[k];
        int g0 = k * Sc;
        int st = W - g0; if (st > Sc) st = Sc; if (st < 0) st = 0;
        int rowb = (n - 1 - g0) * TT;
        for (int s = 0; s < st; ++s) {
            x = bb[rowb + x];
            rowb -= TT;
            s_tags[n - 2 - g0 - s] = x;
        }
    }
    __syncthreads();

    int* orow = out + b * LL;
    #pragma unroll
    for (int k = 0; k < LL / 256; ++k) orow[tid + 256 * k] = s_tags[tid + 256 * k];
}

extern "C" void kernel_launch(void* const* d_in, const int* in_sizes, int n_in,
                              void* d_out, int out_size, void* d_ws, size_t ws_size,
                              hipStream_t stream) {
    const float* feats = (const float*)d_in[0];
    const int*   mask  = (const int*)d_in[1];
    const float* trans = (const float*)d_in[2];
    int* out = (int*)d_out;

    float* Prows = (float*)d_ws;
    unsigned char* Bp = (unsigned char*)d_ws + (size_t)PROWS_ELEMS * sizeof(float);

    k_forward<<<dim3(BB), dim3(64), 0, stream>>>(feats, mask, trans, Prows);
    k_bp<<<dim3(BB, 8), dim3(256), 0, stream>>>(feats, mask, trans, Prows, Bp);
    k_back<<<dim3(BB), dim3(256), 0, stream>>>(mask, trans, Prows, Bp, out);
}

// Round 11
// 375.177 us; speedup vs baseline: 1.0367x; 1.0322x over previous
//
#include <hip/hip_runtime.h>

#define BB 64
#define LL 512
#define TT 52
#define START_TAG 50
#define END_TAG 51

// ws layout: Prows (64*512*52 f32 = 6.8MB) then Bp (64*512*52 u8 = 1.7MB)
#define PROWS_ELEMS (BB * LL * TT)

__device__ __forceinline__ float rdlane(float v, int l) {
    return __int_as_float(__builtin_amdgcn_readlane(__float_as_int(v), l));
}

__device__ __forceinline__ int wave_masksum(const int* mrow, int lane) {
    int partial = 0;
    #pragma unroll
    for (int k = 0; k < LL / 64; ++k) partial += mrow[lane + 64 * k];
    #pragma unroll
    for (int off = 32; off >= 1; off >>= 1) partial += __shfl_xor(partial, off, 64);
    return partial;
}

// X-macro: 52 NAMED scalars (no alloca -> nothing can spill to scratch).
#define REP52(X) \
  X(0) X(1) X(2) X(3) X(4) X(5) X(6) X(7) X(8) X(9) \
  X(10) X(11) X(12) X(13) X(14) X(15) X(16) X(17) X(18) X(19) \
  X(20) X(21) X(22) X(23) X(24) X(25) X(26) X(27) X(28) X(29) \
  X(30) X(31) X(32) X(33) X(34) X(35) X(36) X(37) X(38) X(39) \
  X(40) X(41) X(42) X(43) X(44) X(45) X(46) X(47) X(48) X(49) \
  X(50) X(51)

#define DECL_C(i) float c##i = (lane < TT) ? trans[(i) * TT + lane] : 0.0f;

// 4 independent max chains by residue class (order-independent for max)
#define RCH0(X) X(0) X(4) X(8) X(12) X(16) X(20) X(24) X(28) X(32) X(36) X(40) X(44) X(48)
#define RCH1(X) X(1) X(5) X(9) X(13) X(17) X(21) X(25) X(29) X(33) X(37) X(41) X(45) X(49)
#define RCH2(X) X(2) X(6) X(10) X(14) X(18) X(22) X(26) X(30) X(34) X(38) X(42) X(46) X(50)
#define RCH3(X) X(3) X(7) X(11) X(15) X(19) X(23) X(27) X(31) X(35) X(39) X(43) X(47) X(51)
#define A0(i) b0v = fmaxf(b0v, (f + c##i) + rdlane(bestP, i));
#define A1(i) b1v = fmaxf(b1v, (f + c##i) + rdlane(bestP, i));
#define A2(i) b2v = fmaxf(b2v, (f + c##i) + rdlane(bestP, i));
#define A3(i) b3v = fmaxf(b3v, (f + c##i) + rdlane(bestP, i));

#define FSTEP(tcur)                                                          \
    do {                                                                     \
        float b0v = -3.0e38f, b1v = -3.0e38f, b2v = -3.0e38f, b3v = -3.0e38f;\
        RCH0(A0) RCH1(A1) RCH2(A2) RCH3(A3)                                  \
        bestP = fmaxf(fmaxf(b0v, b1v), fmaxf(b2v, b3v));                     \
        if (lane < TT) arow[(tcur) * TT + lane] = bestP;                     \
    } while (0)

// ---------------- K1: forward recurrence, VALUES ONLY ----------------
// One wave per batch. Lane j holds P[j]. No LDS, no barriers, no arrays, no
// lambdas: c and the feats ring are named scalars -> guaranteed VGPR-resident.
// Exact: value = max over i of (f + c[i]) + P[i]; max is order-independent.
__launch_bounds__(64, 1)
__global__ void k_forward(const float* __restrict__ feats,
                          const int* __restrict__ mask,
                          const float* __restrict__ trans,
                          float* __restrict__ Prows) {
    const int b = blockIdx.x;
    const int lane = threadIdx.x;

    const int n = wave_masksum(mask + b * LL, lane);   // [256,512], uniform

    REP52(DECL_C)

    const float* frow = feats + (size_t)b * LL * TT;
    float* arow = Prows + (size_t)b * LL * TT;

    float bestP = (lane < TT) ? (frow[lane] + c50) : -3.0e38f;   // c50 = trans[START][j]
    if (lane < TT) arow[lane] = bestP;                           // P0

    // 4-deep prefetch ring, named scalars (rows 1..4; n >= 256)
    float f0 = (lane < TT) ? frow[1 * TT + lane] : 0.0f;
    float f1 = (lane < TT) ? frow[2 * TT + lane] : 0.0f;
    float f2 = (lane < TT) ? frow[3 * TT + lane] : 0.0f;
    float f3 = (lane < TT) ? frow[4 * TT + lane] : 0.0f;

    int t = 1;
    for (; t + 3 < n; t += 4) {
        {
            float f = f0;
            int tt = t + 4; if (tt > LL - 1) tt = LL - 1;
            f0 = (lane < TT) ? frow[tt * TT + lane] : 0.0f;
            FSTEP(t);
        }
        {
            float f = f1;
            int tt = t + 5; if (tt > LL - 1) tt = LL - 1;
            f1 = (lane < TT) ? frow[tt * TT + lane] : 0.0f;
            FSTEP(t + 1);
        }
        {
            float f = f2;
            int tt = t + 6; if (tt > LL - 1) tt = LL - 1;
            f2 = (lane < TT) ? frow[tt * TT + lane] : 0.0f;
            FSTEP(t + 2);
        }
        {
            float f = f3;
            int tt = t + 7; if (tt > LL - 1) tt = LL - 1;
            f3 = (lane < TT) ? frow[tt * TT + lane] : 0.0f;
            FSTEP(t + 3);
        }
    }
    // tail <= 3 steps; ring holds rows t, t+1, t+2 in f0,f1,f2
    if (t < n) { float f = f0; FSTEP(t); ++t; }
    if (t < n) { float f = f1; FSTEP(t); ++t; }
    if (t < n) { float f = f2; FSTEP(t); ++t; }
}

// ---------------- K2: parallel backpointer recompute ----------------
// grid (64 batches x 8 t-chunks) x 256 thr. Lane j computes argmax_i
// (f + c[i]) + P_{t-1}[i], strict > ascending scan == first-max-wins ==
// jnp.argmax, operands bit-identical to the reference. Named scalars.
#define BPSTEP(i)                                                            \
    {                                                                        \
        float v = (f + c##i) + rdlane(preg, i);                              \
        bool gt = v > best;                                                  \
        best = gt ? v : best;                                                \
        bi   = gt ? (i) : bi;                                                \
    }

__launch_bounds__(256, 1)
__global__ void k_bp(const float* __restrict__ feats,
                     const int* __restrict__ mask,
                     const float* __restrict__ trans,
                     const float* __restrict__ Prows,
                     unsigned char* __restrict__ Bp) {
    const int b = blockIdx.x;
    const int cch = blockIdx.y;        // 0..7
    const int tid = threadIdx.x;
    const int lane = tid & 63;
    const int w = tid >> 6;

    const int n = wave_masksum(mask + b * LL, lane);

    REP52(DECL_C)

    const float* frow = feats + (size_t)b * LL * TT;
    const float* arow = Prows + (size_t)b * LL * TT;
    unsigned char* brow = Bp + (size_t)b * LL * TT;

    const int t0 = cch * 64 + w * 16;
    for (int r = 0; r < 16; ++r) {
        int t = t0 + r;
        if (t < 1 || t >= n) continue;         // uniform per wave
        float preg = (lane < TT) ? arow[(t - 1) * TT + lane] : 0.0f;
        float f    = (lane < TT) ? frow[t * TT + lane] : 0.0f;
        float best = -3.0e38f;
        int bi = 0;
        REP52(BPSTEP)
        if (lane < TT) brow[t * TT + lane] = (unsigned char)bi;
    }
}

// ---------------- K3: 32-chunk two-phase backtrace + output ----------------
__launch_bounds__(256, 1)
__global__ void k_back(const int* __restrict__ mask,
                       const float* __restrict__ trans,
                       const float* __restrict__ Prows,
                       const unsigned char* __restrict__ Bp,
                       int* __restrict__ out) {
    const int b = blockIdx.x;
    const int tid = threadIdx.x;
    const int lane = tid & 63;

    __shared__ int s_tags[LL];
    __shared__ unsigned char s_map[32 * TT];
    __shared__ int s_ent[32];

    const int n = wave_masksum(mask + b * LL, lane);

    // pointer0 = argmax_i ( P_{n-1}[i] + trans[i, END] ), min-index tie
    const float* arow = Prows + (size_t)b * LL * TT;
    float lv = -3.0e38f;
    int li = lane;
    if (lane < TT) lv = arow[(n - 1) * TT + lane] + trans[lane * TT + END_TAG];
    #pragma unroll
    for (int off = 32; off >= 1; off >>= 1) {
        float ov = __shfl_xor(lv, off, 64);
        int   oi = __shfl_xor(li, off, 64);
        if (ov > lv || (ov == lv && oi < li)) { lv = ov; li = oi; }
    }
    const int ptr0 = li;   // uniform

    #pragma unroll
    for (int k = 0; k < LL / 256; ++k) s_tags[tid + 256 * k] = 0;
    __syncthreads();

    const unsigned char* bb = Bp + (size_t)b * LL * TT;
    const int W  = n - 1;                 // walk length
    const int Sc = (W + 31) >> 5;         // per-chunk steps (>=8)

    // phase 1: 32*52 = 1664 walkers, 7 interleaved chains per thread
    {
        int xs[7], rowb[7], steps[7], kk[7], yy[7];
        #pragma unroll
        for (int c7 = 0; c7 < 7; ++c7) {
            int v = c7 * 256 + tid;
            bool act = v < 32 * TT;
            int k = act ? v / TT : 0;
            int y = act ? v - k * TT : 0;
            int g0 = k * Sc;
            int st = W - g0; if (st > Sc) st = Sc; if (st < 0) st = 0;
            steps[c7] = act ? st : 0;
            rowb[c7] = (n - 1 - g0) * TT;
            xs[c7] = y; kk[c7] = k; yy[c7] = y;
        }
        for (int s = 0; s < Sc; ++s) {
            #pragma unroll
            for (int c7 = 0; c7 < 7; ++c7) {
                if (s < steps[c7]) {
                    xs[c7] = bb[rowb[c7] + xs[c7]];
                    rowb[c7] -= TT;
                }
            }
        }
        #pragma unroll
        for (int c7 = 0; c7 < 7; ++c7) {
            if (c7 * 256 + tid < 32 * TT)
                s_map[kk[c7] * TT + yy[c7]] = (unsigned char)xs[c7];
        }
    }
    __syncthreads();
    if (tid == 0) {
        int e = ptr0; s_ent[0] = e;
        #pragma unroll
        for (int k = 1; k < 32; ++k) { e = s_map[(k - 1) * TT + e]; s_ent[k] = e; }
        s_tags[n - 1] = ptr0;
        s_tags[LL - 1] = ptr0;    // reference quirk: decode[L-1] = pointer0 always
    }
    __syncthreads();
    if (tid < 32) {
        int k = tid;
        int x = s_ent[k];
        int g0 = k * Sc;
        int st = W - g0; if (st > Sc) st = Sc; if (st < 0) st = 0;
        int rowb = (n - 1 - g0) * TT;
        for (int s = 0; s < st; ++s) {
            x = bb[rowb + x];
            rowb -= TT;
            s_tags[n - 2 - g0 - s] = x;
        }
    }
    __syncthreads();

    int* orow = out + b * LL;
    #pragma unroll
    for (int k = 0; k < LL / 256; ++k) orow[tid + 256 * k] = s_tags[tid + 256 * k];
}

extern "C" void kernel_launch(void* const* d_in, const int* in_sizes, int n_in,
                              void* d_out, int out_size, void* d_ws, size_t ws_size,
                              hipStream_t stream) {
    const float* feats = (const float*)d_in[0];
    const int*   mask  = (const int*)d_in[1];
    const float* trans = (const float*)d_in[2];
    int* out = (int*)d_out;

    float* Prows = (float*)d_ws;
    unsigned char* Bp = (unsigned char*)d_ws + (size_t)PROWS_ELEMS * sizeof(float);

    k_forward<<<dim3(BB), dim3(64), 0, stream>>>(feats, mask, trans, Prows);
    k_bp<<<dim3(BB, 8), dim3(256), 0, stream>>>(feats, mask, trans, Prows, Bp);
    k_back<<<dim3(BB), dim3(256), 0, stream>>>(mask, trans, Prows, Bp, out);
}